// Round 11
// baseline (154.105 us; speedup 1.0000x reference)
//
#include <hip/hip_runtime.h>
#include <cstdint>
#include <cstddef>

#define T_DIM 512
#define B_DIM 32
#define E_DIM 512
#define D_DIM 512
#define PAD_IDX 3
#define M_ROWS (T_DIM * B_DIM)   // 16384
#define PF 32                    // scan prefetch depth

typedef __attribute__((ext_vector_type(8))) __bf16 bf16x8;
typedef __attribute__((ext_vector_type(4))) float  f32x4;

__device__ __forceinline__ unsigned short f2bf(float x) {
    union { float f; uint32_t u; } v; v.f = x;
    uint32_t u = v.u;
    uint32_t r = (u + 0x7FFFu + ((u >> 16) & 1u)) >> 16;
    return (unsigned short)r;
}
__device__ __forceinline__ float bf2f(unsigned short h) {
    union { float f; uint32_t u; } v; v.u = ((uint32_t)h) << 16;
    return v.f;
}
__device__ __forceinline__ float fast_sigmoid(float z) {
    return __builtin_amdgcn_rcpf(1.f + __expf(-z));
}
__device__ __forceinline__ float fast_tanh(float x) {
    return 1.f - 2.f * __builtin_amdgcn_rcpf(__expf(2.f * x) + 1.f);
}

// ---------------------------------------------------------------------------
// Fused prep: embed+LN (blocks 0..4095), W transpose+permute (4096..4607),
// W_out convert (4608..5119), gate-bias build (5120..5135). All independent.
// ---------------------------------------------------------------------------
__global__ __launch_bounds__(256) void prep_kernel(
    const int* __restrict__ src, const float* __restrict__ emb,
    const float* __restrict__ g, const float* __restrict__ bb,
    const float* __restrict__ W0, const float* __restrict__ W1,
    const float* __restrict__ b0, const float* __restrict__ b1,
    const float* __restrict__ W_out,
    unsigned short* __restrict__ xn, unsigned short* __restrict__ Wt,
    unsigned short* __restrict__ Wob, float* __restrict__ bias)
{
    __shared__ float tile[64][65];
    const int bx = blockIdx.x;
    if (bx < 4096) {
        // ---- embedding gather + LayerNorm: one wave per row ----
        int wave = threadIdx.x >> 6;
        int lane = threadIdx.x & 63;
        int row  = bx * 4 + wave;
        int tok  = src[row];
        float x[8];
        if (tok == PAD_IDX) {
            #pragma unroll
            for (int j = 0; j < 8; j++) x[j] = 0.f;
        } else {
            const float* er = emb + (size_t)tok * E_DIM + lane * 8;
            f32x4 a0 = *(const f32x4*)(er);
            f32x4 a1 = *(const f32x4*)(er + 4);
            #pragma unroll
            for (int j = 0; j < 4; j++) { x[j] = a0[j]; x[4 + j] = a1[j]; }
        }
        float s = 0.f, sq = 0.f;
        #pragma unroll
        for (int j = 0; j < 8; j++) { s += x[j]; sq += x[j] * x[j]; }
        #pragma unroll
        for (int off = 32; off >= 1; off >>= 1) {
            s  += __shfl_xor(s,  off, 64);
            sq += __shfl_xor(sq, off, 64);
        }
        float mean = s * (1.f / 512.f);
        float var  = sq * (1.f / 512.f) - mean * mean;
        float rs   = rsqrtf(var + 1e-5f);
        f32x4 g0 = *(const f32x4*)(g + lane * 8);
        f32x4 g1 = *(const f32x4*)(g + lane * 8 + 4);
        f32x4 c0 = *(const f32x4*)(bb + lane * 8);
        f32x4 c1 = *(const f32x4*)(bb + lane * 8 + 4);
        unsigned short o[8];
        #pragma unroll
        for (int j = 0; j < 4; j++) {
            o[j]     = f2bf((x[j]     - mean) * rs * g0[j] + c0[j]);
            o[4 + j] = f2bf((x[4 + j] - mean) * rs * g1[j] + c1[j]);
        }
        uint4 pk;
        pk.x = (uint32_t)o[0] | ((uint32_t)o[1] << 16);
        pk.y = (uint32_t)o[2] | ((uint32_t)o[3] << 16);
        pk.z = (uint32_t)o[4] | ((uint32_t)o[5] << 16);
        pk.w = (uint32_t)o[6] | ((uint32_t)o[7] << 16);
        *(uint4*)(xn + (size_t)row * E_DIM + lane * 8) = pk;
    } else if (bx < 4608) {
        // ---- W0/W1 transpose+convert+gate-permute -> Wt [4096][512] ----
        int bxx = bx - 4096;
        int k0  = (bxx & 7) * 64;
        int n0g = (bxx >> 3) * 64;
        int dir = n0g >> 11;
        const float* W = dir ? W1 : W0;
        int d0 = (n0g & 2047) >> 2;
        int tx = threadIdx.x & 63;
        int ty = threadIdx.x >> 6;
        int scol = ((tx >> 4) << 9) + d0 + (tx & 15);
        for (int r = ty; r < 64; r += 4)
            tile[r][tx] = W[(size_t)(k0 + r) * 2048 + scol];
        __syncthreads();
        for (int r2 = ty; r2 < 64; r2 += 4) {
            int j = ((r2 & 3) << 4) | (r2 >> 2);
            Wt[(size_t)(n0g + r2) * 512 + k0 + tx] = f2bf(tile[tx][j]);
        }
    } else if (bx < 5120) {
        // ---- W_out f32 -> bf16 ----
        int i = ((bx - 4608) * 256 + threadIdx.x) * 4;
        f32x4 v = *(const f32x4*)(W_out + i);
        uint2 pk;
        pk.x = (uint32_t)f2bf(v[0]) | ((uint32_t)f2bf(v[1]) << 16);
        pk.y = (uint32_t)f2bf(v[2]) | ((uint32_t)f2bf(v[3]) << 16);
        *(uint2*)(Wob + i) = pk;
    } else {
        // ---- permuted gate-bias: bias[n'] = {0, b[0][d], b[1][d], 0} ----
        int n = (bx - 5120) * 256 + threadIdx.x;
        int dir = n >> 11, gg = n & 3, d = (n & 2047) >> 2;
        const float* bp = dir ? b1 : b0;
        float v = (gg == 1) ? bp[d] : ((gg == 2) ? bp[512 + d] : 0.f);
        bias[n] = v;
    }
}

// ---------------------------------------------------------------------------
// Counted-vmcnt ring-3 bf16 MFMA GEMM (r5/r10 structure — constraint-polytope
// corner: 64x64 waves, ring-3, 72 KiB, 2 blk/CU = 16 waves/CU). GEMM1.
// One {vmcnt(3); lgkmcnt(0); s_barrier} per K-tile; stage 2 tiles ahead.
// Swizzle class f(row)=(row>>1)&3 per 16-B slot, both sides (0 conflicts).
// Grouped XCD raster; K-loop fully unrolled.
// ---------------------------------------------------------------------------
template<int KD, int NMT, int NNT, int GM, int GN, int EPI>
__global__ __launch_bounds__(512, 4) void gemm_pipe_kernel(
    const unsigned short* __restrict__ A,
    const unsigned short* __restrict__ Bt,
    void* __restrict__ Cout,
    const float* __restrict__ bias,
    int ldc)
{
    constexpr int BM = 128, BN = 256;
    constexpr int MR = 4, NR = 4;
    constexpr int NKT = KD / 32;
    constexpr int RA  = BM / 128;
    constexpr int RB  = BN / 128;
    constexpr int LPT = RA + RB;
    constexpr int ASZ = BM * 32;
    constexpr int BSZ = BN * 32;
    __shared__ unsigned short smem[3 * (ASZ + BSZ)];

    const int tid = threadIdx.x;
    const int w   = tid >> 6;
    const int l   = tid & 63;

    constexpr int PER_G = GM * GN;
    constexpr int NGC   = NNT / GN;
    const int bid = blockIdx.x;
    const int c   = bid & 7;
    const int idx = bid >> 3;
    const int gi  = idx / PER_G;
    const int wi  = idx % PER_G;
    const int gg  = c + 8 * gi;
    const int mt  = (gg / NGC) * GM + wi / GN;
    const int nt  = (gg % NGC) * GN + wi % GN;

    const int wm = w >> 2, wn = w & 3;

    const unsigned short* Ab = A  + (size_t)mt * BM * KD;
    const unsigned short* Bb = Bt + (size_t)nt * BN * KD;

    const int srow = w * 16 + (l >> 2);
    const int scol = ((l & 3) ^ ((l >> 3) & 3)) * 8;

    auto stage = [&](int t, int slot) {
        const unsigned short* Ag = Ab + t * 32;
        const unsigned short* Bg = Bb + t * 32;
        unsigned short* As = smem + slot * (ASZ + BSZ);
        unsigned short* Bs = As + ASZ;
        #pragma unroll
        for (int r = 0; r < RA; r++)
            __builtin_amdgcn_global_load_lds(
                (const __attribute__((address_space(1))) void*)(Ag + (size_t)(r * 128 + srow) * KD + scol),
                (__attribute__((address_space(3))) void*)(As + (r * 128 + w * 16) * 32),
                16, 0, 0);
        #pragma unroll
        for (int r = 0; r < RB; r++)
            __builtin_amdgcn_global_load_lds(
                (const __attribute__((address_space(1))) void*)(Bg + (size_t)(r * 128 + srow) * KD + scol),
                (__attribute__((address_space(3))) void*)(Bs + (r * 128 + w * 16) * 32),
                16, 0, 0);
    };

    f32x4 acc[MR][NR];
    #pragma unroll
    for (int m = 0; m < MR; m++)
        #pragma unroll
        for (int n = 0; n < NR; n++)
            acc[m][n] = (f32x4){0.f, 0.f, 0.f, 0.f};

    stage(0, 0); stage(1, 1);

    const int li   = l & 15;
    const int cg   = l >> 4;
    const int rswz = (cg ^ ((li >> 1) & 3)) * 8;

    #pragma unroll
    for (int t = 0; t < NKT; t++) {
        if (t + 1 < NKT)
            asm volatile("s_waitcnt vmcnt(%0) lgkmcnt(0)" :: "n"(LPT) : "memory");
        else
            asm volatile("s_waitcnt vmcnt(0) lgkmcnt(0)" ::: "memory");
        __builtin_amdgcn_s_barrier();
        if (t + 2 < NKT) stage(t + 2, (t + 2) % 3);

        const unsigned short* As = smem + (t % 3) * (ASZ + BSZ);
        const unsigned short* Bs = As + ASZ;
        bf16x8 af[MR], bfv[NR];
        #pragma unroll
        for (int m = 0; m < MR; m++) {
            int row = wm * 64 + m * 16 + li;
            af[m] = *(const bf16x8*)(As + row * 32 + rswz);
        }
        #pragma unroll
        for (int n = 0; n < NR; n++) {
            int row = wn * 64 + n * 16 + li;
            bfv[n] = *(const bf16x8*)(Bs + row * 32 + rswz);
        }
        __builtin_amdgcn_s_setprio(1);
        #pragma unroll
        for (int m = 0; m < MR; m++)
            #pragma unroll
            for (int n = 0; n < NR; n++)
                acc[m][n] = __builtin_amdgcn_mfma_f32_16x16x32_bf16(
                    af[m], bfv[n], acc[m][n], 0, 0, 0);
        __builtin_amdgcn_s_setprio(0);
    }

    // Epilogue: C/D layout col=lane&15, row=(lane>>4)*4+reg
    const int colb = nt * BN + wn * 64;
    const int rowb = mt * BM + wm * 64;
    #pragma unroll
    for (int m = 0; m < MR; m++) {
        #pragma unroll
        for (int n = 0; n < NR; n++) {
            int col  = colb + n * 16 + li;
            int row0 = rowb + m * 16 + cg * 4;
            float bi = bias[col];
            if (EPI == 0) {
                unsigned short* C = (unsigned short*)Cout;
                #pragma unroll
                for (int j = 0; j < 4; j++)
                    C[(size_t)(row0 + j) * ldc + col] = f2bf(acc[m][n][j] + bi);
            } else {
                float* C = (float*)Cout;
                #pragma unroll
                for (int j = 0; j < 4; j++)
                    C[(size_t)(row0 + j) * ldc + col] = fast_tanh(acc[m][n][j] + bi);
            }
        }
    }
}

// ---------------------------------------------------------------------------
// Counted-vmcnt ring-3 GEMM, BM=BN=128, 256 threads (4 waves, 2x2 of 64x64),
// 48 KiB LDS. For GEMM2: 512 blocks -> 2 resident blocks/CU (desynced pair)
// instead of one 8-wave lockstep block. K-loop fully unrolled (r10).
// Same proven race-free ring + swizzle class as above.
// ---------------------------------------------------------------------------
template<int KD, int NMT, int NNT, int GM, int GN, int EPI>
__global__ __launch_bounds__(256, 3) void gemm_ring3_kernel(
    const unsigned short* __restrict__ A,
    const unsigned short* __restrict__ Bt,
    void* __restrict__ Cout,
    const float* __restrict__ bias,
    int ldc)
{
    constexpr int NKT = KD / 32;
    constexpr int LPT = 4;
    constexpr int SLOT = 8192;                 // ushorts (A 4096 + B 4096)
    __shared__ unsigned short smem[3 * SLOT];  // 48 KiB

    const int tid = threadIdx.x;
    const int w   = tid >> 6;
    const int l   = tid & 63;

    constexpr int PER_G = GM * GN;
    constexpr int NGC   = NNT / GN;
    const int bid = blockIdx.x;
    const int c   = bid & 7;
    const int idx = bid >> 3;
    const int gi  = idx / PER_G;
    const int wi  = idx % PER_G;
    const int gg  = c + 8 * gi;
    const int mt  = (gg / NGC) * GM + wi / GN;
    const int nt  = (gg % NGC) * GN + wi % GN;

    const int wm = w >> 1, wn = w & 1;

    const unsigned short* Ab = A  + (size_t)mt * 128 * KD;
    const unsigned short* Bb = Bt + (size_t)nt * 128 * KD;

    const int s_colx = (((l & 3) ^ ((l >> 3) & 3)) * 8);

    auto stage = [&](int t, int slot) {
        const unsigned short* Ag = Ab + t * 32 + s_colx;
        const unsigned short* Bg = Bb + t * 32 + s_colx;
        unsigned short* As = smem + slot * SLOT;
        unsigned short* Bs = As + 4096;
        #pragma unroll
        for (int r = 0; r < 2; r++) {
            int grow = r * 64 + w * 16 + (l >> 2);
            __builtin_amdgcn_global_load_lds(
                (const __attribute__((address_space(1))) void*)(Ag + (size_t)grow * KD),
                (__attribute__((address_space(3))) void*)(As + r * 2048 + w * 512),
                16, 0, 0);
            __builtin_amdgcn_global_load_lds(
                (const __attribute__((address_space(1))) void*)(Bg + (size_t)grow * KD),
                (__attribute__((address_space(3))) void*)(Bs + r * 2048 + w * 512),
                16, 0, 0);
        }
    };

    f32x4 acc[4][4];
    #pragma unroll
    for (int m = 0; m < 4; m++)
        #pragma unroll
        for (int n = 0; n < 4; n++)
            acc[m][n] = (f32x4){0.f, 0.f, 0.f, 0.f};

    stage(0, 0); stage(1, 1);

    const int li   = l & 15;
    const int cg   = l >> 4;
    const int rswz = (cg ^ ((li >> 1) & 3)) * 8;

    #pragma unroll
    for (int t = 0; t < NKT; t++) {
        if (t + 1 < NKT)
            asm volatile("s_waitcnt vmcnt(%0) lgkmcnt(0)" :: "n"(LPT) : "memory");
        else
            asm volatile("s_waitcnt vmcnt(0) lgkmcnt(0)" ::: "memory");
        __builtin_amdgcn_s_barrier();
        if (t + 2 < NKT) stage(t + 2, (t + 2) % 3);

        const unsigned short* As = smem + (t % 3) * SLOT;
        const unsigned short* Bs = As + 4096;
        bf16x8 af[4], bfv[4];
        #pragma unroll
        for (int m = 0; m < 4; m++) {
            int row = wm * 64 + m * 16 + li;
            af[m] = *(const bf16x8*)(As + row * 32 + rswz);
        }
        #pragma unroll
        for (int n = 0; n < 4; n++) {
            int row = wn * 64 + n * 16 + li;
            bfv[n] = *(const bf16x8*)(Bs + row * 32 + rswz);
        }
        __builtin_amdgcn_s_setprio(1);
        #pragma unroll
        for (int m = 0; m < 4; m++)
            #pragma unroll
            for (int n = 0; n < 4; n++)
                acc[m][n] = __builtin_amdgcn_mfma_f32_16x16x32_bf16(
                    af[m], bfv[n], acc[m][n], 0, 0, 0);
        __builtin_amdgcn_s_setprio(0);
    }

    const int colb = nt * 128 + wn * 64;
    const int rowb = mt * 128 + wm * 64;
    #pragma unroll
    for (int m = 0; m < 4; m++) {
        #pragma unroll
        for (int n = 0; n < 4; n++) {
            int col  = colb + n * 16 + li;
            int row0 = rowb + m * 16 + cg * 4;
            float bi = bias[col];
            if (EPI == 0) {
                unsigned short* C = (unsigned short*)Cout;
                #pragma unroll
                for (int j = 0; j < 4; j++)
                    C[(size_t)(row0 + j) * ldc + col] = f2bf(acc[m][n][j] + bi);
            } else {
                float* C = (float*)Cout;
                #pragma unroll
                for (int j = 0; j < 4; j++)
                    C[(size_t)(row0 + j) * ldc + col] = fast_tanh(acc[m][n][j] + bi);
            }
        }
    }
}

// ---------------------------------------------------------------------------
// Bidirectional SRU scan (unchanged, ~HBM roofline).
// ---------------------------------------------------------------------------
__global__ __launch_bounds__(64) void sru_scan_kernel(
    const unsigned short* __restrict__ U,
    const float* __restrict__ v0, const float* __restrict__ v1,
    unsigned short* __restrict__ h,
    float* __restrict__ hidden)
{
    int id  = blockIdx.x * 64 + threadIdx.x;
    int dir = id >> 14;
    int rem = id & 16383;
    int b   = rem >> 9;
    int d   = rem & 511;
    const float* v = dir ? v1 : v0;
    float vf = v[d], vr = v[D_DIM + d];

    int row0  = (dir ? (T_DIM - 1) * B_DIM : 0) + b;
    long step = (long)(dir ? -B_DIM : B_DIM) * 1024;

    const ushort4* lp = (const ushort4*)U + (size_t)row0 * 1024 + dir * 512 + d;
    unsigned short* hp = h + (size_t)row0 * 1024 + dir * 512 + d;

    ushort4 buf[PF];
    #pragma unroll
    for (int p = 0; p < PF; p++) { buf[p] = *lp; lp += step; }

    float c = 0.f;
    for (int tb = 0; tb < T_DIM - PF; tb += PF) {
        #pragma unroll
        for (int p = 0; p < PF; p++) {
            ushort4 q = buf[p];
            buf[p] = *lp; lp += step;
            float x  = bf2f(q.x);
            float uf = bf2f(q.y);
            float ur = bf2f(q.z);
            float xp = bf2f(q.w);
            float f = fast_sigmoid(__fmaf_rn(vf, c, uf));
            float r = fast_sigmoid(__fmaf_rn(vr, c, ur));
            c = __fmaf_rn(f, c - x, x);
            float hv = __fmaf_rn(r, c - xp, xp);
            *hp = f2bf(hv); hp += step;
        }
    }
    #pragma unroll
    for (int p = 0; p < PF; p++) {
        ushort4 q = buf[p];
        float x  = bf2f(q.x);
        float uf = bf2f(q.y);
        float ur = bf2f(q.z);
        float xp = bf2f(q.w);
        float f = fast_sigmoid(__fmaf_rn(vf, c, uf));
        float r = fast_sigmoid(__fmaf_rn(vr, c, ur));
        c = __fmaf_rn(f, c - x, x);
        float hv = __fmaf_rn(r, c - xp, xp);
        *hp = f2bf(hv); hp += step;
    }
    hidden[b * 1024 + dir * 512 + d] = c;
}

// ---------------------------------------------------------------------------
extern "C" void kernel_launch(void* const* d_in, const int* in_sizes, int n_in,
                              void* d_out, int out_size, void* d_ws, size_t ws_size,
                              hipStream_t stream)
{
    const int*   src   = (const int*)  d_in[0];
    const float* emb   = (const float*)d_in[1];
    const float* ln_g  = (const float*)d_in[2];
    const float* ln_b  = (const float*)d_in[3];
    const float* W0    = (const float*)d_in[4];
    const float* W1    = (const float*)d_in[5];
    const float* v0    = (const float*)d_in[6];
    const float* v1    = (const float*)d_in[7];
    const float* b0    = (const float*)d_in[8];
    const float* b1    = (const float*)d_in[9];
    const float* W_out = (const float*)d_in[10];
    const float* b_out = (const float*)d_in[11];

    unsigned short* Wt  = (unsigned short*)d_ws;                       // 4096*512
    unsigned short* Wob = Wt  + (size_t)4096 * 512;                    // 512*1024
    unsigned short* xn  = Wob + (size_t)512 * 1024;                    // 16384*512
    unsigned short* U   = xn  + (size_t)M_ROWS * 512;                  // 16384*4096
    unsigned short* h   = U   + (size_t)M_ROWS * 4096;                 // 16384*1024
    float*          bias4096 = (float*)(h + (size_t)M_ROWS * 1024);    // 4096

    float* out    = (float*)d_out;
    float* hidden = out + (size_t)M_ROWS * D_DIM;
    (void)out;

    // Fused prep: embed+LN | W transpose | W_out convert | bias build
    prep_kernel<<<5136, 256, 0, stream>>>(src, emb, ln_g, ln_b, W0, W1,
                                          b0, b1, W_out, xn, Wt, Wob, bias4096);

    // U = xn @ Wt^T (gate-interleaved cols, gate biases folded) -> 16384 x 4096 bf16
    gemm_pipe_kernel<512, 128, 16, 8, 4, 0>
        <<<2048, 512, 0, stream>>>(xn, Wt, (void*)U, bias4096, 4096);

    sru_scan_kernel<<<512, 64, 0, stream>>>(U, v0, v1, h, hidden);

    // out = tanh(h @ W_out^T + b_out) -> 16384 x 512 f32
    // BN=128: 128 mt x 4 nt = 512 blocks -> 2 desynced blocks/CU
    gemm_ring3_kernel<1024, 128, 4, 8, 2, 1>
        <<<512, 256, 0, stream>>>(h, Wob, (void*)d_out, b_out, 512);
}

// Round 12
// 151.414 us; speedup vs baseline: 1.0178x; 1.0178x over previous
//
#include <hip/hip_runtime.h>
#include <cstdint>
#include <cstddef>

#define T_DIM 512
#define B_DIM 32
#define E_DIM 512
#define D_DIM 512
#define PAD_IDX 3
#define M_ROWS (T_DIM * B_DIM)   // 16384
#define PF 32                    // scan prefetch depth

typedef __attribute__((ext_vector_type(8))) __bf16 bf16x8;
typedef __attribute__((ext_vector_type(4))) float  f32x4;

__device__ __forceinline__ unsigned short f2bf(float x) {
    union { float f; uint32_t u; } v; v.f = x;
    uint32_t u = v.u;
    uint32_t r = (u + 0x7FFFu + ((u >> 16) & 1u)) >> 16;
    return (unsigned short)r;
}
__device__ __forceinline__ float bf2f(unsigned short h) {
    union { float f; uint32_t u; } v; v.u = ((uint32_t)h) << 16;
    return v.f;
}
__device__ __forceinline__ float fast_sigmoid(float z) {
    return __builtin_amdgcn_rcpf(1.f + __expf(-z));
}
__device__ __forceinline__ float fast_tanh(float x) {
    return 1.f - 2.f * __builtin_amdgcn_rcpf(__expf(2.f * x) + 1.f);
}

// ---------------------------------------------------------------------------
// Fused prep: embed+LN (blocks 0..4095), W transpose+permute (4096..4607),
// W_out convert (4608..5119), gate-bias build (5120..5135). All independent.
// ---------------------------------------------------------------------------
__global__ __launch_bounds__(256) void prep_kernel(
    const int* __restrict__ src, const float* __restrict__ emb,
    const float* __restrict__ g, const float* __restrict__ bb,
    const float* __restrict__ W0, const float* __restrict__ W1,
    const float* __restrict__ b0, const float* __restrict__ b1,
    const float* __restrict__ W_out,
    unsigned short* __restrict__ xn, unsigned short* __restrict__ Wt,
    unsigned short* __restrict__ Wob, float* __restrict__ bias)
{
    __shared__ float tile[64][65];
    const int bx = blockIdx.x;
    if (bx < 4096) {
        // ---- embedding gather + LayerNorm: one wave per row ----
        int wave = threadIdx.x >> 6;
        int lane = threadIdx.x & 63;
        int row  = bx * 4 + wave;
        int tok  = src[row];
        float x[8];
        if (tok == PAD_IDX) {
            #pragma unroll
            for (int j = 0; j < 8; j++) x[j] = 0.f;
        } else {
            const float* er = emb + (size_t)tok * E_DIM + lane * 8;
            f32x4 a0 = *(const f32x4*)(er);
            f32x4 a1 = *(const f32x4*)(er + 4);
            #pragma unroll
            for (int j = 0; j < 4; j++) { x[j] = a0[j]; x[4 + j] = a1[j]; }
        }
        float s = 0.f, sq = 0.f;
        #pragma unroll
        for (int j = 0; j < 8; j++) { s += x[j]; sq += x[j] * x[j]; }
        #pragma unroll
        for (int off = 32; off >= 1; off >>= 1) {
            s  += __shfl_xor(s,  off, 64);
            sq += __shfl_xor(sq, off, 64);
        }
        float mean = s * (1.f / 512.f);
        float var  = sq * (1.f / 512.f) - mean * mean;
        float rs   = rsqrtf(var + 1e-5f);
        f32x4 g0 = *(const f32x4*)(g + lane * 8);
        f32x4 g1 = *(const f32x4*)(g + lane * 8 + 4);
        f32x4 c0 = *(const f32x4*)(bb + lane * 8);
        f32x4 c1 = *(const f32x4*)(bb + lane * 8 + 4);
        unsigned short o[8];
        #pragma unroll
        for (int j = 0; j < 4; j++) {
            o[j]     = f2bf((x[j]     - mean) * rs * g0[j] + c0[j]);
            o[4 + j] = f2bf((x[4 + j] - mean) * rs * g1[j] + c1[j]);
        }
        uint4 pk;
        pk.x = (uint32_t)o[0] | ((uint32_t)o[1] << 16);
        pk.y = (uint32_t)o[2] | ((uint32_t)o[3] << 16);
        pk.z = (uint32_t)o[4] | ((uint32_t)o[5] << 16);
        pk.w = (uint32_t)o[6] | ((uint32_t)o[7] << 16);
        *(uint4*)(xn + (size_t)row * E_DIM + lane * 8) = pk;
    } else if (bx < 4608) {
        // ---- W0/W1 transpose+convert+gate-permute -> Wt [4096][512] ----
        int bxx = bx - 4096;
        int k0  = (bxx & 7) * 64;
        int n0g = (bxx >> 3) * 64;
        int dir = n0g >> 11;
        const float* W = dir ? W1 : W0;
        int d0 = (n0g & 2047) >> 2;
        int tx = threadIdx.x & 63;
        int ty = threadIdx.x >> 6;
        int scol = ((tx >> 4) << 9) + d0 + (tx & 15);
        for (int r = ty; r < 64; r += 4)
            tile[r][tx] = W[(size_t)(k0 + r) * 2048 + scol];
        __syncthreads();
        for (int r2 = ty; r2 < 64; r2 += 4) {
            int j = ((r2 & 3) << 4) | (r2 >> 2);
            Wt[(size_t)(n0g + r2) * 512 + k0 + tx] = f2bf(tile[tx][j]);
        }
    } else if (bx < 5120) {
        // ---- W_out f32 -> bf16 ----
        int i = ((bx - 4608) * 256 + threadIdx.x) * 4;
        f32x4 v = *(const f32x4*)(W_out + i);
        uint2 pk;
        pk.x = (uint32_t)f2bf(v[0]) | ((uint32_t)f2bf(v[1]) << 16);
        pk.y = (uint32_t)f2bf(v[2]) | ((uint32_t)f2bf(v[3]) << 16);
        *(uint2*)(Wob + i) = pk;
    } else {
        // ---- permuted gate-bias: bias[n'] = {0, b[0][d], b[1][d], 0} ----
        int n = (bx - 5120) * 256 + threadIdx.x;
        int dir = n >> 11, gg = n & 3, d = (n & 2047) >> 2;
        const float* bp = dir ? b1 : b0;
        float v = (gg == 1) ? bp[d] : ((gg == 2) ? bp[512 + d] : 0.f);
        bias[n] = v;
    }
}

// ---------------------------------------------------------------------------
// Counted-vmcnt ring-3 bf16 MFMA GEMM (r5/r10 structure — measured optimum
// of the explored space: 64x64 waves, 8/block, ring-3, 72 KiB, 2 blk/CU).
// One {vmcnt(3); lgkmcnt(0); s_barrier} per K-tile; stage 2 tiles ahead.
// Race-freedom: iter t reads slot t%3, stages slot (t+2)%3 (last read at
// t-1; each wave's t-1 reads drained by its lgkmcnt(0) before the iter-t
// barrier; staging issued only after that barrier).
// Swizzle class f(row)=(row>>1)&3 per 16-B slot, both sides (0 conflicts
// measured). Grouped XCD raster; K-loop fully unrolled.
// A: [M][KD] bf16 row-major.  Bt: [N][KD] bf16 (N-major).
// EPI=0: C bf16 = acc + bias[col].  EPI=1: C f32 = tanh(acc + bias[col]).
// ---------------------------------------------------------------------------
template<int KD, int NMT, int NNT, int GM, int GN, int EPI>
__global__ __launch_bounds__(512, 4) void gemm_pipe_kernel(
    const unsigned short* __restrict__ A,
    const unsigned short* __restrict__ Bt,
    void* __restrict__ Cout,
    const float* __restrict__ bias,
    int ldc)
{
    constexpr int BM = 128, BN = 256;
    constexpr int MR = 4, NR = 4;
    constexpr int NKT = KD / 32;
    constexpr int RA  = BM / 128;
    constexpr int RB  = BN / 128;
    constexpr int LPT = RA + RB;
    constexpr int ASZ = BM * 32;
    constexpr int BSZ = BN * 32;
    __shared__ unsigned short smem[3 * (ASZ + BSZ)];

    const int tid = threadIdx.x;
    const int w   = tid >> 6;
    const int l   = tid & 63;

    constexpr int PER_G = GM * GN;
    constexpr int NGC   = NNT / GN;
    const int bid = blockIdx.x;
    const int c   = bid & 7;
    const int idx = bid >> 3;
    const int gi  = idx / PER_G;
    const int wi  = idx % PER_G;
    const int gg  = c + 8 * gi;
    const int mt  = (gg / NGC) * GM + wi / GN;
    const int nt  = (gg % NGC) * GN + wi % GN;

    const int wm = w >> 2, wn = w & 3;

    const unsigned short* Ab = A  + (size_t)mt * BM * KD;
    const unsigned short* Bb = Bt + (size_t)nt * BN * KD;

    const int srow = w * 16 + (l >> 2);
    const int scol = ((l & 3) ^ ((l >> 3) & 3)) * 8;

    auto stage = [&](int t, int slot) {
        const unsigned short* Ag = Ab + t * 32;
        const unsigned short* Bg = Bb + t * 32;
        unsigned short* As = smem + slot * (ASZ + BSZ);
        unsigned short* Bs = As + ASZ;
        #pragma unroll
        for (int r = 0; r < RA; r++)
            __builtin_amdgcn_global_load_lds(
                (const __attribute__((address_space(1))) void*)(Ag + (size_t)(r * 128 + srow) * KD + scol),
                (__attribute__((address_space(3))) void*)(As + (r * 128 + w * 16) * 32),
                16, 0, 0);
        #pragma unroll
        for (int r = 0; r < RB; r++)
            __builtin_amdgcn_global_load_lds(
                (const __attribute__((address_space(1))) void*)(Bg + (size_t)(r * 128 + srow) * KD + scol),
                (__attribute__((address_space(3))) void*)(Bs + (r * 128 + w * 16) * 32),
                16, 0, 0);
    };

    f32x4 acc[MR][NR];
    #pragma unroll
    for (int m = 0; m < MR; m++)
        #pragma unroll
        for (int n = 0; n < NR; n++)
            acc[m][n] = (f32x4){0.f, 0.f, 0.f, 0.f};

    stage(0, 0); stage(1, 1);

    const int li   = l & 15;
    const int cg   = l >> 4;
    const int rswz = (cg ^ ((li >> 1) & 3)) * 8;

    #pragma unroll
    for (int t = 0; t < NKT; t++) {
        if (t + 1 < NKT)
            asm volatile("s_waitcnt vmcnt(%0) lgkmcnt(0)" :: "n"(LPT) : "memory");
        else
            asm volatile("s_waitcnt vmcnt(0) lgkmcnt(0)" ::: "memory");
        __builtin_amdgcn_s_barrier();
        if (t + 2 < NKT) stage(t + 2, (t + 2) % 3);

        const unsigned short* As = smem + (t % 3) * (ASZ + BSZ);
        const unsigned short* Bs = As + ASZ;
        bf16x8 af[MR], bfv[NR];
        #pragma unroll
        for (int m = 0; m < MR; m++) {
            int row = wm * 64 + m * 16 + li;
            af[m] = *(const bf16x8*)(As + row * 32 + rswz);
        }
        #pragma unroll
        for (int n = 0; n < NR; n++) {
            int row = wn * 64 + n * 16 + li;
            bfv[n] = *(const bf16x8*)(Bs + row * 32 + rswz);
        }
        __builtin_amdgcn_s_setprio(1);
        #pragma unroll
        for (int m = 0; m < MR; m++)
            #pragma unroll
            for (int n = 0; n < NR; n++)
                acc[m][n] = __builtin_amdgcn_mfma_f32_16x16x32_bf16(
                    af[m], bfv[n], acc[m][n], 0, 0, 0);
        __builtin_amdgcn_s_setprio(0);
    }

    // Epilogue: C/D layout col=lane&15, row=(lane>>4)*4+reg
    const int colb = nt * BN + wn * 64;
    const int rowb = mt * BM + wm * 64;
    #pragma unroll
    for (int m = 0; m < MR; m++) {
        #pragma unroll
        for (int n = 0; n < NR; n++) {
            int col  = colb + n * 16 + li;
            int row0 = rowb + m * 16 + cg * 4;
            float bi = bias[col];
            if (EPI == 0) {
                unsigned short* C = (unsigned short*)Cout;
                #pragma unroll
                for (int j = 0; j < 4; j++)
                    C[(size_t)(row0 + j) * ldc + col] = f2bf(acc[m][n][j] + bi);
            } else {
                float* C = (float*)Cout;
                #pragma unroll
                for (int j = 0; j < 4; j++)
                    C[(size_t)(row0 + j) * ldc + col] = fast_tanh(acc[m][n][j] + bi);
            }
        }
    }
}

// ---------------------------------------------------------------------------
// Bidirectional SRU scan (~88% of HBM roofline).
// One thread per (dir,b,d); gate-interleaved U -> one ushort4/step;
// PF-deep static prefetch pipeline.
// ---------------------------------------------------------------------------
__global__ __launch_bounds__(64) void sru_scan_kernel(
    const unsigned short* __restrict__ U,
    const float* __restrict__ v0, const float* __restrict__ v1,
    unsigned short* __restrict__ h,
    float* __restrict__ hidden)
{
    int id  = blockIdx.x * 64 + threadIdx.x;
    int dir = id >> 14;
    int rem = id & 16383;
    int b   = rem >> 9;
    int d   = rem & 511;
    const float* v = dir ? v1 : v0;
    float vf = v[d], vr = v[D_DIM + d];

    int row0  = (dir ? (T_DIM - 1) * B_DIM : 0) + b;
    long step = (long)(dir ? -B_DIM : B_DIM) * 1024;

    const ushort4* lp = (const ushort4*)U + (size_t)row0 * 1024 + dir * 512 + d;
    unsigned short* hp = h + (size_t)row0 * 1024 + dir * 512 + d;

    ushort4 buf[PF];
    #pragma unroll
    for (int p = 0; p < PF; p++) { buf[p] = *lp; lp += step; }

    float c = 0.f;
    for (int tb = 0; tb < T_DIM - PF; tb += PF) {
        #pragma unroll
        for (int p = 0; p < PF; p++) {
            ushort4 q = buf[p];
            buf[p] = *lp; lp += step;
            float x  = bf2f(q.x);
            float uf = bf2f(q.y);
            float ur = bf2f(q.z);
            float xp = bf2f(q.w);
            float f = fast_sigmoid(__fmaf_rn(vf, c, uf));
            float r = fast_sigmoid(__fmaf_rn(vr, c, ur));
            c = __fmaf_rn(f, c - x, x);
            float hv = __fmaf_rn(r, c - xp, xp);
            *hp = f2bf(hv); hp += step;
        }
    }
    #pragma unroll
    for (int p = 0; p < PF; p++) {
        ushort4 q = buf[p];
        float x  = bf2f(q.x);
        float uf = bf2f(q.y);
        float ur = bf2f(q.z);
        float xp = bf2f(q.w);
        float f = fast_sigmoid(__fmaf_rn(vf, c, uf));
        float r = fast_sigmoid(__fmaf_rn(vr, c, ur));
        c = __fmaf_rn(f, c - x, x);
        float hv = __fmaf_rn(r, c - xp, xp);
        *hp = f2bf(hv); hp += step;
    }
    hidden[b * 1024 + dir * 512 + d] = c;
}

// ---------------------------------------------------------------------------
extern "C" void kernel_launch(void* const* d_in, const int* in_sizes, int n_in,
                              void* d_out, int out_size, void* d_ws, size_t ws_size,
                              hipStream_t stream)
{
    const int*   src   = (const int*)  d_in[0];
    const float* emb   = (const float*)d_in[1];
    const float* ln_g  = (const float*)d_in[2];
    const float* ln_b  = (const float*)d_in[3];
    const float* W0    = (const float*)d_in[4];
    const float* W1    = (const float*)d_in[5];
    const float* v0    = (const float*)d_in[6];
    const float* v1    = (const float*)d_in[7];
    const float* b0    = (const float*)d_in[8];
    const float* b1    = (const float*)d_in[9];
    const float* W_out = (const float*)d_in[10];
    const float* b_out = (const float*)d_in[11];

    unsigned short* Wt  = (unsigned short*)d_ws;                       // 4096*512
    unsigned short* Wob = Wt  + (size_t)4096 * 512;                    // 512*1024
    unsigned short* xn  = Wob + (size_t)512 * 1024;                    // 16384*512
    unsigned short* U   = xn  + (size_t)M_ROWS * 512;                  // 16384*4096
    unsigned short* h   = U   + (size_t)M_ROWS * 4096;                 // 16384*1024
    float*          bias4096 = (float*)(h + (size_t)M_ROWS * 1024);    // 4096

    float* out    = (float*)d_out;
    float* hidden = out + (size_t)M_ROWS * D_DIM;
    (void)out;

    // Fused prep: embed+LN | W transpose | W_out convert | bias build
    prep_kernel<<<5136, 256, 0, stream>>>(src, emb, ln_g, ln_b, W0, W1,
                                          b0, b1, W_out, xn, Wt, Wob, bias4096);

    // U = xn @ Wt^T (gate-interleaved cols, gate biases folded) -> 16384 x 4096 bf16
    gemm_pipe_kernel<512, 128, 16, 8, 4, 0>
        <<<2048, 512, 0, stream>>>(xn, Wt, (void*)U, bias4096, 4096);

    sru_scan_kernel<<<512, 64, 0, stream>>>(U, v0, v1, h, hidden);

    // out = tanh(h @ W_out^T + b_out) -> 16384 x 512 f32
    gemm_pipe_kernel<1024, 128, 2, 8, 2, 1>
        <<<256, 512, 0, stream>>>(h, Wob, (void*)d_out, b_out, 512);
}